// Round 5
// baseline (199.415 us; speedup 1.0000x reference)
//
#include <hip/hip_runtime.h>

typedef _Float16 half8 __attribute__((ext_vector_type(8)));
typedef _Float16 half4 __attribute__((ext_vector_type(4)));
typedef float f32x4 __attribute__((ext_vector_type(4)));

#define ATT_SCALE 0.03125f   // 1/sqrt(1024)
#define S_LEN 2048
#define D_DIM 1024
#define NB 4

// async 16B HBM -> LDS copy (gfx950 global_load_lds_dwordx4).
// LDS dest must be wave-uniform base; HW adds lane*16.
__device__ __forceinline__ void async_cp16(const _Float16* g, _Float16* l)
{
    __builtin_amdgcn_global_load_lds(
        (const __attribute__((address_space(1))) void*)g,
        (__attribute__((address_space(3))) void*)l, 16, 0, 0);
}

// ---------------------------------------------------------------------------
// Legacy 128x128 GEMM core (m97 structure) — still used by scores_exp / pv.
// ---------------------------------------------------------------------------
__device__ __forceinline__ void gemm_core(const _Float16* __restrict__ Ag,
                                          const _Float16* __restrict__ Bg,
                                          int lda, int ldb, int ksteps,
                                          f32x4 acc[4][4])
{
    __shared__ _Float16 As[128 * 32];
    __shared__ _Float16 Bs[128 * 32];

    const int t    = threadIdx.x;
    const int wave = t >> 6;
    const int lane = t & 63;
    const int wm   = (wave >> 1) * 64;
    const int wn   = (wave & 1) * 64;
    const int lg   = lane >> 4;
    const int lr   = lane & 15;

    const int c0 = t,        r0 = c0 >> 2, h0 = (c0 & 3) * 8;
    const int c1 = 256 + t,  r1 = c1 >> 2, h1 = (c1 & 3) * 8;
    const int lb0 = (wave * 64) * 8;
    const int lb1 = (256 + wave * 64) * 8;

    const _Float16* a0p = Ag + (long)r0 * lda + h0;
    const _Float16* a1p = Ag + (long)r1 * lda + h1;
    const _Float16* b0p = Bg + (long)r0 * ldb + h0;
    const _Float16* b1p = Bg + (long)r1 * ldb + h1;

    for (int ks = 0; ks < ksteps; ++ks) {
        __syncthreads();
        async_cp16(a0p, As + lb0);
        async_cp16(a1p, As + lb1);
        async_cp16(b0p, Bs + lb0);
        async_cp16(b1p, Bs + lb1);
        __syncthreads();

        a0p += 32; a1p += 32; b0p += 32; b1p += 32;

        half8 af[4], bf[4];
#pragma unroll
        for (int i = 0; i < 4; ++i)
            af[i] = *(const half8*)&As[(wm + i * 16 + lr) * 32 + lg * 8];
#pragma unroll
        for (int j = 0; j < 4; ++j)
            bf[j] = *(const half8*)&Bs[(wn + j * 16 + lr) * 32 + lg * 8];

#pragma unroll
        for (int i = 0; i < 4; ++i)
#pragma unroll
            for (int j = 0; j < 4; ++j)
                acc[i][j] = __builtin_amdgcn_mfma_f32_16x16x32_f16(af[i], bf[j], acc[i][j], 0, 0, 0);
    }
}

// ---------------------------------------------------------------------------
// 0a) zero row sums (8192 floats)
// ---------------------------------------------------------------------------
__global__ void zero_sums_kernel(float* __restrict__ rs)
{
    rs[blockIdx.x * 256 + threadIdx.x] = 0.f;
}

// ---------------------------------------------------------------------------
// 0b) zero output (split-K pv accumulates with atomicAdd)
// ---------------------------------------------------------------------------
__global__ void zero_out_kernel(float4* __restrict__ p, long n4)
{
    const float4 z = {0.f, 0.f, 0.f, 0.f};
    for (long i = (long)blockIdx.x * blockDim.x + threadIdx.x; i < n4;
         i += (long)gridDim.x * blockDim.x)
        p[i] = z;
}

// ---------------------------------------------------------------------------
// 1) cast x (fp32) -> fp16
// ---------------------------------------------------------------------------
__global__ void cast_x_kernel(const float* __restrict__ X, _Float16* __restrict__ Xh, int n)
{
    int i = blockIdx.x * blockDim.x + threadIdx.x;
    if (i * 4 >= n) return;
    float4 v = ((const float4*)X)[i];
    half4 h;
    h.x = (_Float16)v.x; h.y = (_Float16)v.y; h.z = (_Float16)v.z; h.w = (_Float16)v.w;
    ((half4*)Xh)[i] = h;
}

// ---------------------------------------------------------------------------
// 2) transpose+cast Wq/Wk/Wv [k][n] fp32 -> Wt [w][n][k] fp16
// ---------------------------------------------------------------------------
__global__ void transpose_w_kernel(const float* __restrict__ Wq,
                                   const float* __restrict__ Wk,
                                   const float* __restrict__ Wv,
                                   _Float16* __restrict__ Wt)
{
    __shared__ float tile[32][33];
    const int n0 = blockIdx.x * 32, k0 = blockIdx.y * 32, w = blockIdx.z;
    const float* Wsrc = (w == 0) ? Wq : (w == 1) ? Wk : Wv;
    _Float16* dst = Wt + (long)w * D_DIM * D_DIM;
    const int tx = threadIdx.x, ty = threadIdx.y;
#pragma unroll
    for (int j = 0; j < 4; ++j)
        tile[ty + 8 * j][tx] = Wsrc[(long)(k0 + ty + 8 * j) * D_DIM + n0 + tx];
    __syncthreads();
#pragma unroll
    for (int j = 0; j < 4; ++j)
        dst[(long)(n0 + ty + 8 * j) * D_DIM + k0 + tx] = (_Float16)tile[tx][ty + 8 * j];
}

// ---------------------------------------------------------------------------
// 3) QKV projection, 8-phase 256x256 schedule (T2+T3+T4+T5).
//    512 thr / 8 waves (2Mx4N); per-wave out 128x64 = acc[8][4].
//    LDS 128 KiB: 2 dbuf x (A 256x64 + B 256x64) halves, LINEAR layout with
//    T2 XOR-swizzle applied on BOTH the per-lane global source and the
//    ds_read address (rule 21): byte ^= (row&7)<<4 within each 128 B row.
//    Staging: one full K-tile burst-issued one tile ahead; counted vmcnt(8)
//    at the tile boundary (T4 — never drain to 0 in the loop).
//    grid: 384 blocks, XCD-chunked: per XCD 4 mt x 12 (w,nt); consecutive
//    blocks share the A-panel (L2 reuse).
// ---------------------------------------------------------------------------
__global__ __launch_bounds__(512, 2) void proj_kernel(const _Float16* __restrict__ Xh,
                                                      const _Float16* __restrict__ Wt,
                                                      _Float16* __restrict__ Q,
                                                      _Float16* __restrict__ K,
                                                      _Float16* __restrict__ V)
{
    __shared__ _Float16 As[2][256 * 64];
    __shared__ _Float16 Bs[2][256 * 64];

    const int bid = blockIdx.x;                    // 0..383
    const int g   = (bid & 7) * 48 + (bid >> 3);   // bijective XCD chunking
    const int mt  = g / 12;
    const int rem = g % 12;
    const int w   = rem >> 2;
    const int nt  = rem & 3;

    const int t    = threadIdx.x;
    const int wave = t >> 6;
    const int lane = t & 63;
    const int wr   = wave >> 2;        // 0..1  (M half)
    const int wc   = wave & 3;         // 0..3  (N quarter)
    const int lg   = lane >> 4;
    const int lr   = lane & 15;

    const _Float16* Ag = Xh + (long)mt * 256 * D_DIM;
    const _Float16* Bg = Wt + (long)w * D_DIM * D_DIM + (long)nt * 256 * D_DIM;

    // staging decomposition: wave-instr i covers LDS bytes
    // [i*8192 + wave*1024 + lane*16): row = i*64 + wave*8 + (lane>>3),
    // row&7 == lane>>3, so the inverse swizzle is lane-only:
    const int rsel = lane >> 3;
    const int csel = ((lane & 7) ^ rsel) * 8;      // halves within row
    const int w8   = wave * 8;
    const int ldst = wave * 512;                   // halves; + i*4096

#define STAGE_TILE(dstA, dstB, kt1)                                             \
    {                                                                           \
        _Pragma("unroll")                                                       \
        for (int i_ = 0; i_ < 4; ++i_)                                          \
            async_cp16(Ag + (long)(i_ * 64 + w8 + rsel) * D_DIM + (kt1) * 64 + csel, \
                       (dstA) + i_ * 4096 + ldst);                              \
        _Pragma("unroll")                                                       \
        for (int i_ = 0; i_ < 4; ++i_)                                          \
            async_cp16(Bg + (long)(i_ * 64 + w8 + rsel) * D_DIM + (kt1) * 64 + csel, \
                       (dstB) + i_ * 4096 + ldst);                              \
    }

    f32x4 acc[8][4];
#pragma unroll
    for (int i = 0; i < 8; ++i)
#pragma unroll
        for (int j = 0; j < 4; ++j) acc[i][j] = (f32x4){0.f, 0.f, 0.f, 0.f};

    STAGE_TILE(As[0], Bs[0], 0);

    const int cswz = (lr & 7) << 4;
    const int nkt  = D_DIM / 64;   // 16

    for (int kt = 0; kt < nkt; ++kt) {
        const int d = kt & 1;
        if (kt > 0) __builtin_amdgcn_s_barrier();   // all reads of buf d^1 done
        if (kt + 1 < nkt) {
            STAGE_TILE(As[d ^ 1], Bs[d ^ 1], kt + 1);
            asm volatile("s_waitcnt vmcnt(8)" ::: "memory");  // tile kt resident
        } else {
            asm volatile("s_waitcnt vmcnt(0)" ::: "memory");
        }
        __builtin_amdgcn_s_barrier();

        const char* Ab = (const char*)As[d];
        const char* Bb = (const char*)Bs[d];
#pragma unroll
        for (int kh = 0; kh < 2; ++kh) {
            const int cb = (kh * 64 + lg * 16) ^ cswz;
            half8 bf[4];
#pragma unroll
            for (int j = 0; j < 4; ++j)
                bf[j] = *(const half8*)(Bb + (wc * 64 + j * 16 + lr) * 128 + cb);
#pragma unroll
            for (int mh = 0; mh < 2; ++mh) {
                half8 af[4];
#pragma unroll
                for (int i = 0; i < 4; ++i)
                    af[i] = *(const half8*)(Ab + (wr * 128 + (mh * 4 + i) * 16 + lr) * 128 + cb);
                __builtin_amdgcn_s_setprio(1);
#pragma unroll
                for (int i = 0; i < 4; ++i)
#pragma unroll
                    for (int j = 0; j < 4; ++j)
                        acc[mh * 4 + i][j] = __builtin_amdgcn_mfma_f32_16x16x32_f16(
                            af[i], bf[j], acc[mh * 4 + i][j], 0, 0, 0);
                __builtin_amdgcn_s_setprio(0);
                if (!(kh == 1 && mh == 1)) __builtin_amdgcn_s_barrier();
            }
        }
    }
#undef STAGE_TILE

    _Float16* C = (w == 0) ? Q : (w == 1) ? K : V;
    const long row0 = (long)mt * 256 + wr * 128 + lg * 4;
    const long col0 = (long)nt * 256 + wc * 64 + lr;
#pragma unroll
    for (int mf = 0; mf < 8; ++mf)
#pragma unroll
        for (int j = 0; j < 4; ++j)
#pragma unroll
            for (int rr = 0; rr < 4; ++rr)
                C[(row0 + mf * 16 + rr) * D_DIM + col0 + j * 16] = (_Float16)acc[mf][j][rr];
}

// ---------------------------------------------------------------------------
// 4) transpose V [b][s][d] -> Vt [b][d][s] (fp16), half8 both ways.
// ---------------------------------------------------------------------------
__global__ __launch_bounds__(256) void transpose_v_kernel(const _Float16* __restrict__ V,
                                                          _Float16* __restrict__ Vt)
{
    __shared__ _Float16 tile[64][72];
    const int d0 = blockIdx.x * 64, s0 = blockIdx.y * 64;
    const long b = blockIdx.z;
    const _Float16* Vb = V + b * S_LEN * D_DIM;
    _Float16* Vtb = Vt + b * D_DIM * S_LEN;
    const int t = threadIdx.x;
    const int sr = t >> 3, c8 = (t & 7) * 8;

    *(half8*)&tile[sr][c8]      = *(const half8*)&Vb[(long)(s0 + sr) * D_DIM + d0 + c8];
    *(half8*)&tile[sr + 32][c8] = *(const half8*)&Vb[(long)(s0 + sr + 32) * D_DIM + d0 + c8];
    __syncthreads();

    const int dr = t >> 3, s8 = (t & 7) * 8;
    half8 o0, o1;
#pragma unroll
    for (int e = 0; e < 8; ++e) {
        o0[e] = tile[s8 + e][dr];
        o1[e] = tile[s8 + e][dr + 32];
    }
    *(half8*)&Vtb[(long)(d0 + dr) * S_LEN + s0 + s8]      = o0;
    *(half8*)&Vtb[(long)(d0 + dr + 32) * S_LEN + s0 + s8] = o1;
}

// ---------------------------------------------------------------------------
// 5) fused scores+exp (unchanged round-4 structure)
// ---------------------------------------------------------------------------
__global__ __launch_bounds__(256) void scores_exp_kernel(const _Float16* __restrict__ Q,
                                                         const _Float16* __restrict__ K,
                                                         _Float16* __restrict__ P,
                                                         float* __restrict__ row_sum)
{
    const int xcd = blockIdx.x & 7;
    const int idx = blockIdx.x >> 3;      // 0..67
    const int b   = idx / 17;
    const int l   = idx % 17;
    int qt, kt;
    if (l <= xcd) { qt = xcd;      kt = l; }
    else          { qt = 15 - xcd; kt = l - xcd - 1; }

    f32x4 acc[4][4];
#pragma unroll
    for (int i = 0; i < 4; ++i)
#pragma unroll
        for (int j = 0; j < 4; ++j) acc[i][j] = (f32x4){0.f, 0.f, 0.f, 0.f};

    const _Float16* Ag = Q + ((long)b * S_LEN + qt * 128) * D_DIM;
    const _Float16* Bg = K + ((long)b * S_LEN + kt * 128) * D_DIM;
    gemm_core(Ag, Bg, D_DIM, D_DIM, D_DIM / 32, acc);

    _Float16* Pb = P + (long)b * S_LEN * S_LEN;
    float* rsb = row_sum + (long)b * S_LEN;
    const int t = threadIdx.x, wave = t >> 6, lane = t & 63;
    const int wm = (wave >> 1) * 64, wn = (wave & 1) * 64;
    const int lg = lane >> 4, lr = lane & 15;
    const int row0 = qt * 128 + wm + 4 * lg;
    const int col0 = kt * 128 + wn + lr;

#pragma unroll
    for (int i = 0; i < 4; ++i) {
#pragma unroll
        for (int r = 0; r < 4; ++r) {
            const int row = row0 + i * 16 + r;
            float s = 0.f;
#pragma unroll
            for (int j = 0; j < 4; ++j) {
                const int col = col0 + j * 16;
                float p = (col <= row) ? __expf(acc[i][j][r] * ATT_SCALE) : 0.f;
                s += p;
                Pb[(long)row * S_LEN + col] = (_Float16)p;
            }
#pragma unroll
            for (int off = 1; off < 16; off <<= 1) s += __shfl_xor(s, off, 64);
            if (lr == 0) atomicAdd(&rsb[row], s);
        }
    }
}

// ---------------------------------------------------------------------------
// 6) O = (P @ V) / row_sum, split-K + XCD balance (unchanged round-4).
// ---------------------------------------------------------------------------
__global__ __launch_bounds__(256) void pv_kernel(const _Float16* __restrict__ P,
                                                 const _Float16* __restrict__ Vt,
                                                 const float* __restrict__ row_sum,
                                                 float* __restrict__ O)
{
    const int xcd = blockIdx.x & 7;
    int r = blockIdx.x >> 3;              // 0..95
    const int b = r / 24;  r %= 24;
    const int j = r >> 3;
    const int nt = r & 7;
    const int sl = (j == 0) ? (7 - xcd) : (j == 1 ? 8 + 2 * xcd : 9 + 2 * xcd);

    int qt, k0s, ks;
    if (sl < 8) { qt = sl; k0s = 0; ks = (qt + 1) * 4; }
    else {
        const int e = sl - 8;
        qt = 8 + (e >> 1);
        ks = (qt + 1) * 2;
        k0s = (e & 1) * ks;
    }

    f32x4 acc[4][4];
#pragma unroll
    for (int i = 0; i < 4; ++i)
#pragma unroll
        for (int jj = 0; jj < 4; ++jj) acc[i][jj] = (f32x4){0.f, 0.f, 0.f, 0.f};

    const _Float16* Ag = P + ((long)b * S_LEN + qt * 128) * S_LEN + k0s * 32;
    const _Float16* Bg = Vt + (long)b * D_DIM * S_LEN + (long)nt * 128 * S_LEN + k0s * 32;
    gemm_core(Ag, Bg, S_LEN, S_LEN, ks, acc);

    float* Ob = O + (long)b * S_LEN * D_DIM;
    const float* rsb = row_sum + (long)b * S_LEN;
    const int t = threadIdx.x, wave = t >> 6, lane = t & 63;
    const int wm = (wave >> 1) * 64, wn = (wave & 1) * 64;
    const int lg = lane >> 4, lr = lane & 15;
    const long row0 = qt * 128 + wm + 4 * lg;
    const long col0 = (long)nt * 128 + wn + lr;

    if (sl < 8) {
#pragma unroll
        for (int i = 0; i < 4; ++i)
#pragma unroll
            for (int rr = 0; rr < 4; ++rr) {
                const float inv = 1.f / rsb[row0 + i * 16 + rr];
#pragma unroll
                for (int jj = 0; jj < 4; ++jj)
                    Ob[(row0 + i * 16 + rr) * D_DIM + col0 + jj * 16] = acc[i][jj][rr] * inv;
            }
    } else {
#pragma unroll
        for (int i = 0; i < 4; ++i)
#pragma unroll
            for (int rr = 0; rr < 4; ++rr) {
                const float inv = 1.f / rsb[row0 + i * 16 + rr];
#pragma unroll
                for (int jj = 0; jj < 4; ++jj)
                    atomicAdd(&Ob[(row0 + i * 16 + rr) * D_DIM + col0 + jj * 16],
                              acc[i][jj][rr] * inv);
            }
    }
}

// ---------------------------------------------------------------------------
// Workspace layout (MiB offsets), total ~119 MiB:
//   Q [0,16) K [16,32) V [32,48) Vt [48,64) Xh [64,80) Wt [80,86)
//   P [86,118)  row_sum [118, 118+32KiB)
// ---------------------------------------------------------------------------
extern "C" void kernel_launch(void* const* d_in, const int* in_sizes, int n_in,
                              void* d_out, int out_size, void* d_ws, size_t ws_size,
                              hipStream_t stream)
{
    const float* x  = (const float*)d_in[0];
    const float* Wq = (const float*)d_in[1];
    const float* Wk = (const float*)d_in[2];
    const float* Wv = (const float*)d_in[3];
    float* out = (float*)d_out;

    char* ws = (char*)d_ws;
    const long MiB = 1024 * 1024;
    _Float16* Q  = (_Float16*)(ws + 0 * MiB);
    _Float16* K  = (_Float16*)(ws + 16 * MiB);
    _Float16* V  = (_Float16*)(ws + 32 * MiB);
    _Float16* Vt = (_Float16*)(ws + 48 * MiB);
    _Float16* Xh = (_Float16*)(ws + 64 * MiB);
    _Float16* Wt = (_Float16*)(ws + 80 * MiB);
    _Float16* P  = (_Float16*)(ws + 86 * MiB);
    float*    RS = (float*)   (ws + 118 * MiB);

    const int nX = in_sizes[0];   // 8388608

    zero_sums_kernel<<<dim3(NB * S_LEN / 256), dim3(256), 0, stream>>>(RS);
    zero_out_kernel<<<dim3(2048), dim3(256), 0, stream>>>((float4*)out,
                                                          (long)NB * S_LEN * D_DIM / 4);
    cast_x_kernel<<<dim3((nX / 4 + 255) / 256), dim3(256), 0, stream>>>(x, Xh, nX);
    transpose_w_kernel<<<dim3(32, 32, 3), dim3(32, 8), 0, stream>>>(Wq, Wk, Wv, Wt);
    proj_kernel<<<dim3(384), dim3(512), 0, stream>>>(Xh, Wt, Q, K, V);
    transpose_v_kernel<<<dim3(16, 32, 4), dim3(256), 0, stream>>>(V, Vt);
    scores_exp_kernel<<<dim3(544), dim3(256), 0, stream>>>(Q, K, P, RS);
    pv_kernel<<<dim3(768), dim3(256), 0, stream>>>(P, Vt, RS, out);
}

// Round 6
// 189.092 us; speedup vs baseline: 1.0546x; 1.0546x over previous
//
#include <hip/hip_runtime.h>

typedef _Float16 half8 __attribute__((ext_vector_type(8)));
typedef _Float16 half4 __attribute__((ext_vector_type(4)));
typedef float f32x4 __attribute__((ext_vector_type(4)));

#define ATT_SCALE 0.03125f   // 1/sqrt(1024)
#define S_LEN 2048
#define D_DIM 1024
#define NB 4

// async 16B HBM -> LDS copy (gfx950 global_load_lds_dwordx4).
// LDS dest must be wave-uniform base; HW adds lane*16.
__device__ __forceinline__ void async_cp16(const _Float16* g, _Float16* l)
{
    __builtin_amdgcn_global_load_lds(
        (const __attribute__((address_space(1))) void*)g,
        (__attribute__((address_space(3))) void*)l, 16, 0, 0);
}

// ---------------------------------------------------------------------------
// Legacy 128x128 GEMM core (m97 structure) — used by scores_exp / pv.
// ---------------------------------------------------------------------------
__device__ __forceinline__ void gemm_core(const _Float16* __restrict__ Ag,
                                          const _Float16* __restrict__ Bg,
                                          int lda, int ldb, int ksteps,
                                          f32x4 acc[4][4])
{
    __shared__ _Float16 As[128 * 32];
    __shared__ _Float16 Bs[128 * 32];

    const int t    = threadIdx.x;
    const int wave = t >> 6;
    const int lane = t & 63;
    const int wm   = (wave >> 1) * 64;
    const int wn   = (wave & 1) * 64;
    const int lg   = lane >> 4;
    const int lr   = lane & 15;

    const int c0 = t,        r0 = c0 >> 2, h0 = (c0 & 3) * 8;
    const int c1 = 256 + t,  r1 = c1 >> 2, h1 = (c1 & 3) * 8;
    const int lb0 = (wave * 64) * 8;
    const int lb1 = (256 + wave * 64) * 8;

    const _Float16* a0p = Ag + (long)r0 * lda + h0;
    const _Float16* a1p = Ag + (long)r1 * lda + h1;
    const _Float16* b0p = Bg + (long)r0 * ldb + h0;
    const _Float16* b1p = Bg + (long)r1 * ldb + h1;

    for (int ks = 0; ks < ksteps; ++ks) {
        __syncthreads();
        async_cp16(a0p, As + lb0);
        async_cp16(a1p, As + lb1);
        async_cp16(b0p, Bs + lb0);
        async_cp16(b1p, Bs + lb1);
        __syncthreads();

        a0p += 32; a1p += 32; b0p += 32; b1p += 32;

        half8 af[4], bf[4];
#pragma unroll
        for (int i = 0; i < 4; ++i)
            af[i] = *(const half8*)&As[(wm + i * 16 + lr) * 32 + lg * 8];
#pragma unroll
        for (int j = 0; j < 4; ++j)
            bf[j] = *(const half8*)&Bs[(wn + j * 16 + lr) * 32 + lg * 8];

#pragma unroll
        for (int i = 0; i < 4; ++i)
#pragma unroll
            for (int j = 0; j < 4; ++j)
                acc[i][j] = __builtin_amdgcn_mfma_f32_16x16x32_f16(af[i], bf[j], acc[i][j], 0, 0, 0);
    }
}

// ---------------------------------------------------------------------------
// 0a) zero row sums (8192 floats)
// ---------------------------------------------------------------------------
__global__ void zero_sums_kernel(float* __restrict__ rs)
{
    rs[blockIdx.x * 256 + threadIdx.x] = 0.f;
}

// ---------------------------------------------------------------------------
// 0b) zero output (split-K pv accumulates with atomicAdd)
// ---------------------------------------------------------------------------
__global__ void zero_out_kernel(float4* __restrict__ p, long n4)
{
    const float4 z = {0.f, 0.f, 0.f, 0.f};
    for (long i = (long)blockIdx.x * blockDim.x + threadIdx.x; i < n4;
         i += (long)gridDim.x * blockDim.x)
        p[i] = z;
}

// ---------------------------------------------------------------------------
// 1) cast x (fp32) -> fp16
// ---------------------------------------------------------------------------
__global__ void cast_x_kernel(const float* __restrict__ X, _Float16* __restrict__ Xh, int n)
{
    int i = blockIdx.x * blockDim.x + threadIdx.x;
    if (i * 4 >= n) return;
    float4 v = ((const float4*)X)[i];
    half4 h;
    h.x = (_Float16)v.x; h.y = (_Float16)v.y; h.z = (_Float16)v.z; h.w = (_Float16)v.w;
    ((half4*)Xh)[i] = h;
}

// ---------------------------------------------------------------------------
// 2) transpose+cast Wq/Wk/Wv [k][n] fp32 -> Wt [w][n][k] fp16
// ---------------------------------------------------------------------------
__global__ void transpose_w_kernel(const float* __restrict__ Wq,
                                   const float* __restrict__ Wk,
                                   const float* __restrict__ Wv,
                                   _Float16* __restrict__ Wt)
{
    __shared__ float tile[32][33];
    const int n0 = blockIdx.x * 32, k0 = blockIdx.y * 32, w = blockIdx.z;
    const float* Wsrc = (w == 0) ? Wq : (w == 1) ? Wk : Wv;
    _Float16* dst = Wt + (long)w * D_DIM * D_DIM;
    const int tx = threadIdx.x, ty = threadIdx.y;
#pragma unroll
    for (int j = 0; j < 4; ++j)
        tile[ty + 8 * j][tx] = Wsrc[(long)(k0 + ty + 8 * j) * D_DIM + n0 + tx];
    __syncthreads();
#pragma unroll
    for (int j = 0; j < 4; ++j)
        dst[(long)(n0 + ty + 8 * j) * D_DIM + k0 + tx] = (_Float16)tile[tx][ty + 8 * j];
}

// ---------------------------------------------------------------------------
// 3) QKV projection — fine-interleaved pipelined schedule (T2+T3+T4+T5).
//    BM=256, BN=128, BK=64; 768 tiles = exactly 3 balanced dispatch rounds.
//    512 thr / 8 waves (2M x 4N); per-wave out 128x32 = 8 M-frags x 2 N-frags.
//    LDS: TRIPLE-buffered ring (A 32KB + B 16KB per slot, 144 KiB total) ->
//    staging runs 2 tiles ahead; boundary wait is the counted vmcnt(6)
//    (exactly one tile's 6 loads left in flight) — never drains to 0 except
//    the kt==14 boundary (T4). T2 XOR-swizzle byte^=(row&7)<<4 on BOTH the
//    per-lane global source and the ds_read address (HW-verified 0-conflict
//    in round 5). 2 phases per K-tile, each: {ds_read frags; issue stage
//    piece of tile kt+2; s_barrier; lgkmcnt(0); setprio(1); 16 MFMA;
//    setprio(0); [boundary vmcnt]; s_barrier}.
// ---------------------------------------------------------------------------
__global__ __launch_bounds__(512, 1) void proj_kernel(const _Float16* __restrict__ Xh,
                                                      const _Float16* __restrict__ Wt,
                                                      _Float16* __restrict__ Q,
                                                      _Float16* __restrict__ K,
                                                      _Float16* __restrict__ V)
{
    __shared__ _Float16 As3[3][256 * 64];   // 96 KiB
    __shared__ _Float16 Bs3[3][128 * 64];   // 48 KiB

    const int bid = blockIdx.x;                    // 0..767
    const int g   = (bid & 7) * 96 + (bid >> 3);   // bijective XCD chunking
    const int w   = g >> 8;                        // g/256
    const int mt  = (g & 255) >> 3;                // 0..31
    const int nt  = g & 7;                         // 0..7

    const int t    = threadIdx.x;
    const int wave = t >> 6;
    const int lane = t & 63;
    const int wr   = wave >> 2;        // 0..1  (M half)
    const int wc   = wave & 3;         // 0..3  (N quarter, 32 cols each)
    const int lg   = lane >> 4;
    const int lr   = lane & 15;

    const _Float16* Ag = Xh + (long)mt * 256 * D_DIM;
    const _Float16* Bg = Wt + (long)w * D_DIM * D_DIM + (long)nt * 128 * D_DIM;

    // staging: row-within-64-segment = wave*8 + lane>>3; row&7 == lane>>3, so
    // the inverse source swizzle is lane-only:
    const int rsel = lane >> 3;
    const int csel = ((lane & 7) ^ rsel) * 8;      // halves
    const int srow = wave * 8 + rsel;
    const int ldst = wave * 512;                   // halves within 64-row seg

    // A tile = 2 units of 128 rows (2 loads each); B tile = 1 unit. 6 loads/tile.
#define STAGE_A(wb, kt2)                                                        \
    {                                                                           \
        _Pragma("unroll")                                                       \
        for (int u_ = 0; u_ < 2; ++u_)                                          \
            _Pragma("unroll")                                                   \
            for (int l_ = 0; l_ < 2; ++l_)                                      \
                async_cp16(Ag + (long)(u_ * 128 + l_ * 64 + srow) * D_DIM +      \
                               (kt2) * 64 + csel,                               \
                           As3[wb] + u_ * 8192 + l_ * 4096 + ldst);             \
    }
#define STAGE_B(wb, kt2)                                                        \
    {                                                                           \
        _Pragma("unroll")                                                       \
        for (int l_ = 0; l_ < 2; ++l_)                                          \
            async_cp16(Bg + (long)(l_ * 64 + srow) * D_DIM + (kt2) * 64 + csel, \
                       Bs3[wb] + l_ * 4096 + ldst);                             \
    }

    f32x4 acc[8][2];
#pragma unroll
    for (int i = 0; i < 8; ++i)
#pragma unroll
        for (int j = 0; j < 2; ++j) acc[i][j] = (f32x4){0.f, 0.f, 0.f, 0.f};

    // prologue: stage tiles 0 and 1; counted wait leaves tile 1 in flight
    STAGE_A(0, 0); STAGE_B(0, 0);
    STAGE_A(1, 1); STAGE_B(1, 1);
    asm volatile("s_waitcnt vmcnt(6)" ::: "memory");
    __builtin_amdgcn_s_barrier();

    const int cswz = (lr & 7) << 4;
    int rd = 0, wb = 2;

    for (int kt = 0; kt < 16; ++kt) {
        const char* Ab = (const char*)As3[rd];
        const char* Bb = (const char*)Bs3[rd];

        // ---- phase 1: B frags + A frags (mf 0..3), stage A of tile kt+2 ----
        half8 bf[2][2], af[2][4];
#pragma unroll
        for (int kk = 0; kk < 2; ++kk) {
            const int cb = (kk * 64 + lg * 16) ^ cswz;
#pragma unroll
            for (int nf = 0; nf < 2; ++nf)
                bf[kk][nf] = *(const half8*)(Bb + (wc * 32 + nf * 16 + lr) * 128 + cb);
#pragma unroll
            for (int mf = 0; mf < 4; ++mf)
                af[kk][mf] = *(const half8*)(Ab + (wr * 128 + mf * 16 + lr) * 128 + cb);
        }
        if (kt < 14) STAGE_A(wb, kt + 2);
        __builtin_amdgcn_s_barrier();
        asm volatile("s_waitcnt lgkmcnt(0)" ::: "memory");
        __builtin_amdgcn_sched_barrier(0);
        __builtin_amdgcn_s_setprio(1);
#pragma unroll
        for (int kk = 0; kk < 2; ++kk)
#pragma unroll
            for (int mf = 0; mf < 4; ++mf)
#pragma unroll
                for (int nf = 0; nf < 2; ++nf)
                    acc[mf][nf] = __builtin_amdgcn_mfma_f32_16x16x32_f16(
                        af[kk][mf], bf[kk][nf], acc[mf][nf], 0, 0, 0);
        __builtin_amdgcn_s_setprio(0);
        __builtin_amdgcn_s_barrier();

        // ---- phase 2: A frags (mf 4..7), stage B of tile kt+2, boundary ----
        half8 a2[2][4];
#pragma unroll
        for (int kk = 0; kk < 2; ++kk) {
            const int cb = (kk * 64 + lg * 16) ^ cswz;
#pragma unroll
            for (int mf = 0; mf < 4; ++mf)
                a2[kk][mf] = *(const half8*)(Ab + (wr * 128 + (4 + mf) * 16 + lr) * 128 + cb);
        }
        if (kt < 14) STAGE_B(wb, kt + 2);
        __builtin_amdgcn_s_barrier();
        asm volatile("s_waitcnt lgkmcnt(0)" ::: "memory");
        __builtin_amdgcn_sched_barrier(0);
        __builtin_amdgcn_s_setprio(1);
#pragma unroll
        for (int kk = 0; kk < 2; ++kk)
#pragma unroll
            for (int mf = 0; mf < 4; ++mf)
#pragma unroll
                for (int nf = 0; nf < 2; ++nf)
                    acc[4 + mf][nf] = __builtin_amdgcn_mfma_f32_16x16x32_f16(
                        a2[kk][mf], bf[kk][nf], acc[4 + mf][nf], 0, 0, 0);
        __builtin_amdgcn_s_setprio(0);
        if (kt == 14)     asm volatile("s_waitcnt vmcnt(0)" ::: "memory");
        else if (kt < 14) asm volatile("s_waitcnt vmcnt(6)" ::: "memory");
        __builtin_amdgcn_s_barrier();

        rd = (rd == 2) ? 0 : rd + 1;
        wb = (wb == 2) ? 0 : wb + 1;
    }
#undef STAGE_A
#undef STAGE_B

    _Float16* C = (w == 0) ? Q : (w == 1) ? K : V;
    const long row0 = (long)mt * 256 + wr * 128 + lg * 4;
    const long col0 = (long)nt * 128 + wc * 32 + lr;
#pragma unroll
    for (int mf = 0; mf < 8; ++mf)
#pragma unroll
        for (int nf = 0; nf < 2; ++nf)
#pragma unroll
            for (int rr = 0; rr < 4; ++rr)
                C[(row0 + mf * 16 + rr) * D_DIM + col0 + nf * 16] = (_Float16)acc[mf][nf][rr];
}

// ---------------------------------------------------------------------------
// 4) transpose V [b][s][d] -> Vt [b][d][s] (fp16), half8 both ways.
// ---------------------------------------------------------------------------
__global__ __launch_bounds__(256) void transpose_v_kernel(const _Float16* __restrict__ V,
                                                          _Float16* __restrict__ Vt)
{
    __shared__ _Float16 tile[64][72];
    const int d0 = blockIdx.x * 64, s0 = blockIdx.y * 64;
    const long b = blockIdx.z;
    const _Float16* Vb = V + b * S_LEN * D_DIM;
    _Float16* Vtb = Vt + b * D_DIM * S_LEN;
    const int t = threadIdx.x;
    const int sr = t >> 3, c8 = (t & 7) * 8;

    *(half8*)&tile[sr][c8]      = *(const half8*)&Vb[(long)(s0 + sr) * D_DIM + d0 + c8];
    *(half8*)&tile[sr + 32][c8] = *(const half8*)&Vb[(long)(s0 + sr + 32) * D_DIM + d0 + c8];
    __syncthreads();

    const int dr = t >> 3, s8 = (t & 7) * 8;
    half8 o0, o1;
#pragma unroll
    for (int e = 0; e < 8; ++e) {
        o0[e] = tile[s8 + e][dr];
        o1[e] = tile[s8 + e][dr + 32];
    }
    *(half8*)&Vtb[(long)(d0 + dr) * S_LEN + s0 + s8]      = o0;
    *(half8*)&Vtb[(long)(d0 + dr + 32) * S_LEN + s0 + s8] = o1;
}

// ---------------------------------------------------------------------------
// 5) fused scores+exp (m97 core; unchanged round-4 structure)
// ---------------------------------------------------------------------------
__global__ __launch_bounds__(256) void scores_exp_kernel(const _Float16* __restrict__ Q,
                                                         const _Float16* __restrict__ K,
                                                         _Float16* __restrict__ P,
                                                         float* __restrict__ row_sum)
{
    const int xcd = blockIdx.x & 7;
    const int idx = blockIdx.x >> 3;      // 0..67
    const int b   = idx / 17;
    const int l   = idx % 17;
    int qt, kt;
    if (l <= xcd) { qt = xcd;      kt = l; }
    else          { qt = 15 - xcd; kt = l - xcd - 1; }

    f32x4 acc[4][4];
#pragma unroll
    for (int i = 0; i < 4; ++i)
#pragma unroll
        for (int j = 0; j < 4; ++j) acc[i][j] = (f32x4){0.f, 0.f, 0.f, 0.f};

    const _Float16* Ag = Q + ((long)b * S_LEN + qt * 128) * D_DIM;
    const _Float16* Bg = K + ((long)b * S_LEN + kt * 128) * D_DIM;
    gemm_core(Ag, Bg, D_DIM, D_DIM, D_DIM / 32, acc);

    _Float16* Pb = P + (long)b * S_LEN * S_LEN;
    float* rsb = row_sum + (long)b * S_LEN;
    const int t = threadIdx.x, wave = t >> 6, lane = t & 63;
    const int wm = (wave >> 1) * 64, wn = (wave & 1) * 64;
    const int lg = lane >> 4, lr = lane & 15;
    const int row0 = qt * 128 + wm + 4 * lg;
    const int col0 = kt * 128 + wn + lr;

#pragma unroll
    for (int i = 0; i < 4; ++i) {
#pragma unroll
        for (int r = 0; r < 4; ++r) {
            const int row = row0 + i * 16 + r;
            float s = 0.f;
#pragma unroll
            for (int j = 0; j < 4; ++j) {
                const int col = col0 + j * 16;
                float p = (col <= row) ? __expf(acc[i][j][r] * ATT_SCALE) : 0.f;
                s += p;
                Pb[(long)row * S_LEN + col] = (_Float16)p;
            }
#pragma unroll
            for (int off = 1; off < 16; off <<= 1) s += __shfl_xor(s, off, 64);
            if (lr == 0) atomicAdd(&rsb[row], s);
        }
    }
}

// ---------------------------------------------------------------------------
// 6) O = (P @ V) / row_sum, split-K + XCD balance (m97 core; unchanged).
// ---------------------------------------------------------------------------
__global__ __launch_bounds__(256) void pv_kernel(const _Float16* __restrict__ P,
                                                 const _Float16* __restrict__ Vt,
                                                 const float* __restrict__ row_sum,
                                                 float* __restrict__ O)
{
    const int xcd = blockIdx.x & 7;
    int r = blockIdx.x >> 3;              // 0..95
    const int b = r / 24;  r %= 24;
    const int j = r >> 3;
    const int nt = r & 7;
    const int sl = (j == 0) ? (7 - xcd) : (j == 1 ? 8 + 2 * xcd : 9 + 2 * xcd);

    int qt, k0s, ks;
    if (sl < 8) { qt = sl; k0s = 0; ks = (qt + 1) * 4; }
    else {
        const int e = sl - 8;
        qt = 8 + (e >> 1);
        ks = (qt + 1) * 2;
        k0s = (e & 1) * ks;
    }

    f32x4 acc[4][4];
#pragma unroll
    for (int i = 0; i < 4; ++i)
#pragma unroll
        for (int jj = 0; jj < 4; ++jj) acc[i][jj] = (f32x4){0.f, 0.f, 0.f, 0.f};

    const _Float16* Ag = P + ((long)b * S_LEN + qt * 128) * S_LEN + k0s * 32;
    const _Float16* Bg = Vt + (long)b * D_DIM * S_LEN + (long)nt * 128 * S_LEN + k0s * 32;
    gemm_core(Ag, Bg, S_LEN, S_LEN, ks, acc);

    float* Ob = O + (long)b * S_LEN * D_DIM;
    const float* rsb = row_sum + (long)b * S_LEN;
    const int t = threadIdx.x, wave = t >> 6, lane = t & 63;
    const int wm = (wave >> 1) * 64, wn = (wave & 1) * 64;
    const int lg = lane >> 4, lr = lane & 15;
    const long row0 = qt * 128 + wm + 4 * lg;
    const long col0 = (long)nt * 128 + wn + lr;

    if (sl < 8) {
#pragma unroll
        for (int i = 0; i < 4; ++i)
#pragma unroll
            for (int rr = 0; rr < 4; ++rr) {
                const float inv = 1.f / rsb[row0 + i * 16 + rr];
#pragma unroll
                for (int jj = 0; jj < 4; ++jj)
                    Ob[(row0 + i * 16 + rr) * D_DIM + col0 + jj * 16] = acc[i][jj][rr] * inv;
            }
    } else {
#pragma unroll
        for (int i = 0; i < 4; ++i)
#pragma unroll
            for (int rr = 0; rr < 4; ++rr) {
                const float inv = 1.f / rsb[row0 + i * 16 + rr];
#pragma unroll
                for (int jj = 0; jj < 4; ++jj)
                    atomicAdd(&Ob[(row0 + i * 16 + rr) * D_DIM + col0 + jj * 16],
                              acc[i][jj][rr] * inv);
            }
    }
}

// ---------------------------------------------------------------------------
// Workspace layout (MiB offsets), total ~119 MiB:
//   Q [0,16) K [16,32) V [32,48) Vt [48,64) Xh [64,80) Wt [80,86)
//   P [86,118)  row_sum [118, 118+32KiB)
// ---------------------------------------------------------------------------
extern "C" void kernel_launch(void* const* d_in, const int* in_sizes, int n_in,
                              void* d_out, int out_size, void* d_ws, size_t ws_size,
                              hipStream_t stream)
{
    const float* x  = (const float*)d_in[0];
    const float* Wq = (const float*)d_in[1];
    const float* Wk = (const float*)d_in[2];
    const float* Wv = (const float*)d_in[3];
    float* out = (float*)d_out;

    char* ws = (char*)d_ws;
    const long MiB = 1024 * 1024;
    _Float16* Q  = (_Float16*)(ws + 0 * MiB);
    _Float16* K  = (_Float16*)(ws + 16 * MiB);
    _Float16* V  = (_Float16*)(ws + 32 * MiB);
    _Float16* Vt = (_Float16*)(ws + 48 * MiB);
    _Float16* Xh = (_Float16*)(ws + 64 * MiB);
    _Float16* Wt = (_Float16*)(ws + 80 * MiB);
    _Float16* P  = (_Float16*)(ws + 86 * MiB);
    float*    RS = (float*)   (ws + 118 * MiB);

    const int nX = in_sizes[0];   // 8388608

    zero_sums_kernel<<<dim3(NB * S_LEN / 256), dim3(256), 0, stream>>>(RS);
    zero_out_kernel<<<dim3(2048), dim3(256), 0, stream>>>((float4*)out,
                                                          (long)NB * S_LEN * D_DIM / 4);
    cast_x_kernel<<<dim3((nX / 4 + 255) / 256), dim3(256), 0, stream>>>(x, Xh, nX);
    transpose_w_kernel<<<dim3(32, 32, 3), dim3(32, 8), 0, stream>>>(Wq, Wk, Wv, Wt);
    proj_kernel<<<dim3(768), dim3(512), 0, stream>>>(Xh, Wt, Q, K, V);
    transpose_v_kernel<<<dim3(16, 32, 4), dim3(256), 0, stream>>>(V, Vt);
    scores_exp_kernel<<<dim3(544), dim3(256), 0, stream>>>(Q, K, P, RS);
    pv_kernel<<<dim3(768), dim3(256), 0, stream>>>(P, Vt, RS, out);
}

// Round 7
// 188.076 us; speedup vs baseline: 1.0603x; 1.0054x over previous
//
#include <hip/hip_runtime.h>

typedef _Float16 half8 __attribute__((ext_vector_type(8)));
typedef _Float16 half4 __attribute__((ext_vector_type(4)));
typedef float f32x4 __attribute__((ext_vector_type(4)));

#define ATT_SCALE 0.03125f   // 1/sqrt(1024)
#define S_LEN 2048
#define D_DIM 1024
#define NB 4

// async 16B HBM -> LDS copy (gfx950 global_load_lds_dwordx4).
// LDS dest must be wave-uniform base; HW adds lane*16.
__device__ __forceinline__ void async_cp16(const _Float16* g, _Float16* l)
{
    __builtin_amdgcn_global_load_lds(
        (const __attribute__((address_space(1))) void*)g,
        (__attribute__((address_space(3))) void*)l, 16, 0, 0);
}

// ---------------------------------------------------------------------------
// Legacy 128x128 GEMM core (m97 structure) — used by scores_exp / pv.
// ---------------------------------------------------------------------------
__device__ __forceinline__ void gemm_core(const _Float16* __restrict__ Ag,
                                          const _Float16* __restrict__ Bg,
                                          int lda, int ldb, int ksteps,
                                          f32x4 acc[4][4])
{
    __shared__ _Float16 As[128 * 32];
    __shared__ _Float16 Bs[128 * 32];

    const int t    = threadIdx.x;
    const int wave = t >> 6;
    const int lane = t & 63;
    const int wm   = (wave >> 1) * 64;
    const int wn   = (wave & 1) * 64;
    const int lg   = lane >> 4;
    const int lr   = lane & 15;

    const int c0 = t,        r0 = c0 >> 2, h0 = (c0 & 3) * 8;
    const int c1 = 256 + t,  r1 = c1 >> 2, h1 = (c1 & 3) * 8;
    const int lb0 = (wave * 64) * 8;
    const int lb1 = (256 + wave * 64) * 8;

    const _Float16* a0p = Ag + (long)r0 * lda + h0;
    const _Float16* a1p = Ag + (long)r1 * lda + h1;
    const _Float16* b0p = Bg + (long)r0 * ldb + h0;
    const _Float16* b1p = Bg + (long)r1 * ldb + h1;

    for (int ks = 0; ks < ksteps; ++ks) {
        __syncthreads();
        async_cp16(a0p, As + lb0);
        async_cp16(a1p, As + lb1);
        async_cp16(b0p, Bs + lb0);
        async_cp16(b1p, Bs + lb1);
        __syncthreads();

        a0p += 32; a1p += 32; b0p += 32; b1p += 32;

        half8 af[4], bf[4];
#pragma unroll
        for (int i = 0; i < 4; ++i)
            af[i] = *(const half8*)&As[(wm + i * 16 + lr) * 32 + lg * 8];
#pragma unroll
        for (int j = 0; j < 4; ++j)
            bf[j] = *(const half8*)&Bs[(wn + j * 16 + lr) * 32 + lg * 8];

#pragma unroll
        for (int i = 0; i < 4; ++i)
#pragma unroll
            for (int j = 0; j < 4; ++j)
                acc[i][j] = __builtin_amdgcn_mfma_f32_16x16x32_f16(af[i], bf[j], acc[i][j], 0, 0, 0);
    }
}

// ---------------------------------------------------------------------------
// 0a) zero row sums (8192 floats)
// ---------------------------------------------------------------------------
__global__ void zero_sums_kernel(float* __restrict__ rs)
{
    rs[blockIdx.x * 256 + threadIdx.x] = 0.f;
}

// ---------------------------------------------------------------------------
// 0b) zero output (split-K pv accumulates with atomicAdd)
// ---------------------------------------------------------------------------
__global__ void zero_out_kernel(float4* __restrict__ p, long n4)
{
    const float4 z = {0.f, 0.f, 0.f, 0.f};
    for (long i = (long)blockIdx.x * blockDim.x + threadIdx.x; i < n4;
         i += (long)gridDim.x * blockDim.x)
        p[i] = z;
}

// ---------------------------------------------------------------------------
// 1) cast x (fp32) -> fp16
// ---------------------------------------------------------------------------
__global__ void cast_x_kernel(const float* __restrict__ X, _Float16* __restrict__ Xh, int n)
{
    int i = blockIdx.x * blockDim.x + threadIdx.x;
    if (i * 4 >= n) return;
    float4 v = ((const float4*)X)[i];
    half4 h;
    h.x = (_Float16)v.x; h.y = (_Float16)v.y; h.z = (_Float16)v.z; h.w = (_Float16)v.w;
    ((half4*)Xh)[i] = h;
}

// ---------------------------------------------------------------------------
// 2) transpose+cast Wq/Wk/Wv [k][n] fp32 -> Wt [w][n][k] fp16
// ---------------------------------------------------------------------------
__global__ void transpose_w_kernel(const float* __restrict__ Wq,
                                   const float* __restrict__ Wk,
                                   const float* __restrict__ Wv,
                                   _Float16* __restrict__ Wt)
{
    __shared__ float tile[32][33];
    const int n0 = blockIdx.x * 32, k0 = blockIdx.y * 32, w = blockIdx.z;
    const float* Wsrc = (w == 0) ? Wq : (w == 1) ? Wk : Wv;
    _Float16* dst = Wt + (long)w * D_DIM * D_DIM;
    const int tx = threadIdx.x, ty = threadIdx.y;
#pragma unroll
    for (int j = 0; j < 4; ++j)
        tile[ty + 8 * j][tx] = Wsrc[(long)(k0 + ty + 8 * j) * D_DIM + n0 + tx];
    __syncthreads();
#pragma unroll
    for (int j = 0; j < 4; ++j)
        dst[(long)(n0 + ty + 8 * j) * D_DIM + k0 + tx] = (_Float16)tile[tx][ty + 8 * j];
}

// ---------------------------------------------------------------------------
// 3) QKV projection — fine-interleaved pipelined schedule, round-7 shape:
//    BM=128, BN=256, BK=64; grid 64mt x 4nt x 3w = 768 blocks = exactly 3
//    balanced rounds. 512 thr / 8 waves as 2M x 4N -> per-wave 64x64 =
//    acc[4][4]; per phase only 8 ds_read_b128 + 16 MFMA per wave (read:MFMA
//    ratio 0.5, cascade-friendly). LDS triple-ring: slot = A 128x64 (16 KiB)
//    + B 256x64 (32 KiB), 144 KiB total; staging 6 gload_lds/tile (A2+B4)
//    issued 2 tiles ahead; boundary vmcnt(6) never drains in-loop (T4).
//    T2 XOR-swizzle byte^=(row&7)<<4 on source + read (HW-verified 0-conflict
//    rounds 5/6). Phases split by kk (K=32 halves of BK=64).
// ---------------------------------------------------------------------------
__global__ __launch_bounds__(512, 1) void proj_kernel(const _Float16* __restrict__ Xh,
                                                      const _Float16* __restrict__ Wt,
                                                      _Float16* __restrict__ Q,
                                                      _Float16* __restrict__ K,
                                                      _Float16* __restrict__ V)
{
    __shared__ _Float16 As3[3][128 * 64];   // 48 KiB
    __shared__ _Float16 Bs3[3][256 * 64];   // 96 KiB

    const int bid = blockIdx.x;                    // 0..767
    const int g   = (bid & 7) * 96 + (bid >> 3);   // bijective XCD chunking
    const int w   = g >> 8;                        // 0..2
    const int mt  = (g & 255) >> 2;                // 0..63
    const int nt  = g & 3;                         // 0..3

    const int t    = threadIdx.x;
    const int wave = t >> 6;
    const int lane = t & 63;
    const int wr   = wave >> 2;        // 0..1  (M half, 64 rows)
    const int wc   = wave & 3;         // 0..3  (N quarter, 64 cols)
    const int lg   = lane >> 4;
    const int lr   = lane & 15;

    const _Float16* Ag = Xh + (long)mt * 128 * D_DIM;
    const _Float16* Bg = Wt + (long)w * D_DIM * D_DIM + (long)nt * 256 * D_DIM;

    // staging: each gload_lds instr covers 64 rows x 64 halves (8 KiB);
    // row-within-segment = wave*8 + lane>>3; row&7 == lane>>3 -> the inverse
    // source swizzle is lane-only:
    const int rsel = lane >> 3;
    const int csel = ((lane & 7) ^ rsel) * 8;      // halves
    const int srow = wave * 8 + rsel;
    const int ldst = wave * 512;                   // halves within 64-row seg

#define STAGE_A(wb, kt2)                                                        \
    {                                                                           \
        _Pragma("unroll")                                                       \
        for (int u_ = 0; u_ < 2; ++u_)                                          \
            async_cp16(Ag + (long)(u_ * 64 + srow) * D_DIM + (kt2) * 64 + csel, \
                       As3[wb] + u_ * 4096 + ldst);                             \
    }
#define STAGE_B01(wb, kt2)                                                      \
    {                                                                           \
        _Pragma("unroll")                                                       \
        for (int v_ = 0; v_ < 2; ++v_)                                          \
            async_cp16(Bg + (long)(v_ * 64 + srow) * D_DIM + (kt2) * 64 + csel, \
                       Bs3[wb] + v_ * 4096 + ldst);                             \
    }
#define STAGE_B23(wb, kt2)                                                      \
    {                                                                           \
        _Pragma("unroll")                                                       \
        for (int v_ = 2; v_ < 4; ++v_)                                          \
            async_cp16(Bg + (long)(v_ * 64 + srow) * D_DIM + (kt2) * 64 + csel, \
                       Bs3[wb] + v_ * 4096 + ldst);                             \
    }

    f32x4 acc[4][4];
#pragma unroll
    for (int i = 0; i < 4; ++i)
#pragma unroll
        for (int j = 0; j < 4; ++j) acc[i][j] = (f32x4){0.f, 0.f, 0.f, 0.f};

    // prologue: stage tiles 0,1; counted wait leaves tile 1's 6 loads in flight
    STAGE_A(0, 0); STAGE_B01(0, 0); STAGE_B23(0, 0);
    STAGE_A(1, 1); STAGE_B01(1, 1); STAGE_B23(1, 1);
    asm volatile("s_waitcnt vmcnt(6)" ::: "memory");
    __builtin_amdgcn_s_barrier();

    const int cswz = (lr & 7) << 4;
    int rd = 0, wb = 2;

    for (int kt = 0; kt < 16; ++kt) {
        const char* Ab = (const char*)As3[rd];
        const char* Bb = (const char*)Bs3[rd];

        // ---- phase 1 (kk=0): 8 ds_reads; stage A + B01 of tile kt+2 ----
        {
            const int cb = (lg * 16) ^ cswz;
            half8 af[4], bf[4];
#pragma unroll
            for (int nf = 0; nf < 4; ++nf)
                bf[nf] = *(const half8*)(Bb + (wc * 64 + nf * 16 + lr) * 128 + cb);
#pragma unroll
            for (int mf = 0; mf < 4; ++mf)
                af[mf] = *(const half8*)(Ab + (wr * 64 + mf * 16 + lr) * 128 + cb);
            if (kt < 14) { STAGE_A(wb, kt + 2); STAGE_B01(wb, kt + 2); }
            __builtin_amdgcn_s_barrier();
            asm volatile("s_waitcnt lgkmcnt(0)" ::: "memory");
            __builtin_amdgcn_sched_barrier(0);
            __builtin_amdgcn_s_setprio(1);
#pragma unroll
            for (int mf = 0; mf < 4; ++mf)
#pragma unroll
                for (int nf = 0; nf < 4; ++nf)
                    acc[mf][nf] = __builtin_amdgcn_mfma_f32_16x16x32_f16(
                        af[mf], bf[nf], acc[mf][nf], 0, 0, 0);
            __builtin_amdgcn_s_setprio(0);
            __builtin_amdgcn_s_barrier();
        }

        // ---- phase 2 (kk=1): 8 ds_reads; stage B23 of tile kt+2; boundary ----
        {
            const int cb = (64 + lg * 16) ^ cswz;
            half8 af[4], bf[4];
#pragma unroll
            for (int nf = 0; nf < 4; ++nf)
                bf[nf] = *(const half8*)(Bb + (wc * 64 + nf * 16 + lr) * 128 + cb);
#pragma unroll
            for (int mf = 0; mf < 4; ++mf)
                af[mf] = *(const half8*)(Ab + (wr * 64 + mf * 16 + lr) * 128 + cb);
            if (kt < 14) STAGE_B23(wb, kt + 2);
            __builtin_amdgcn_s_barrier();
            asm volatile("s_waitcnt lgkmcnt(0)" ::: "memory");
            __builtin_amdgcn_sched_barrier(0);
            __builtin_amdgcn_s_setprio(1);
#pragma unroll
            for (int mf = 0; mf < 4; ++mf)
#pragma unroll
                for (int nf = 0; nf < 4; ++nf)
                    acc[mf][nf] = __builtin_amdgcn_mfma_f32_16x16x32_f16(
                        af[mf], bf[nf], acc[mf][nf], 0, 0, 0);
            __builtin_amdgcn_s_setprio(0);
            if (kt == 14)     asm volatile("s_waitcnt vmcnt(0)" ::: "memory");
            else if (kt < 14) asm volatile("s_waitcnt vmcnt(6)" ::: "memory");
            __builtin_amdgcn_s_barrier();
        }

        rd = (rd == 2) ? 0 : rd + 1;
        wb = (wb == 2) ? 0 : wb + 1;
    }
#undef STAGE_A
#undef STAGE_B01
#undef STAGE_B23

    _Float16* C = (w == 0) ? Q : (w == 1) ? K : V;
    const long row0 = (long)mt * 128 + wr * 64 + lg * 4;
    const long col0 = (long)nt * 256 + wc * 64 + lr;
#pragma unroll
    for (int mf = 0; mf < 4; ++mf)
#pragma unroll
        for (int nf = 0; nf < 4; ++nf)
#pragma unroll
            for (int rr = 0; rr < 4; ++rr)
                C[(row0 + mf * 16 + rr) * D_DIM + col0 + nf * 16] = (_Float16)acc[mf][nf][rr];
}

// ---------------------------------------------------------------------------
// 4) transpose V [b][s][d] -> Vt [b][d][s] (fp16), half8 both ways.
// ---------------------------------------------------------------------------
__global__ __launch_bounds__(256) void transpose_v_kernel(const _Float16* __restrict__ V,
                                                          _Float16* __restrict__ Vt)
{
    __shared__ _Float16 tile[64][72];
    const int d0 = blockIdx.x * 64, s0 = blockIdx.y * 64;
    const long b = blockIdx.z;
    const _Float16* Vb = V + b * S_LEN * D_DIM;
    _Float16* Vtb = Vt + b * D_DIM * S_LEN;
    const int t = threadIdx.x;
    const int sr = t >> 3, c8 = (t & 7) * 8;

    *(half8*)&tile[sr][c8]      = *(const half8*)&Vb[(long)(s0 + sr) * D_DIM + d0 + c8];
    *(half8*)&tile[sr + 32][c8] = *(const half8*)&Vb[(long)(s0 + sr + 32) * D_DIM + d0 + c8];
    __syncthreads();

    const int dr = t >> 3, s8 = (t & 7) * 8;
    half8 o0, o1;
#pragma unroll
    for (int e = 0; e < 8; ++e) {
        o0[e] = tile[s8 + e][dr];
        o1[e] = tile[s8 + e][dr + 32];
    }
    *(half8*)&Vtb[(long)(d0 + dr) * S_LEN + s0 + s8]      = o0;
    *(half8*)&Vtb[(long)(d0 + dr + 32) * S_LEN + s0 + s8] = o1;
}

// ---------------------------------------------------------------------------
// 5) fused scores+exp (m97 core; unchanged round-4 structure)
// ---------------------------------------------------------------------------
__global__ __launch_bounds__(256) void scores_exp_kernel(const _Float16* __restrict__ Q,
                                                         const _Float16* __restrict__ K,
                                                         _Float16* __restrict__ P,
                                                         float* __restrict__ row_sum)
{
    const int xcd = blockIdx.x & 7;
    const int idx = blockIdx.x >> 3;      // 0..67
    const int b   = idx / 17;
    const int l   = idx % 17;
    int qt, kt;
    if (l <= xcd) { qt = xcd;      kt = l; }
    else          { qt = 15 - xcd; kt = l - xcd - 1; }

    f32x4 acc[4][4];
#pragma unroll
    for (int i = 0; i < 4; ++i)
#pragma unroll
        for (int j = 0; j < 4; ++j) acc[i][j] = (f32x4){0.f, 0.f, 0.f, 0.f};

    const _Float16* Ag = Q + ((long)b * S_LEN + qt * 128) * D_DIM;
    const _Float16* Bg = K + ((long)b * S_LEN + kt * 128) * D_DIM;
    gemm_core(Ag, Bg, D_DIM, D_DIM, D_DIM / 32, acc);

    _Float16* Pb = P + (long)b * S_LEN * S_LEN;
    float* rsb = row_sum + (long)b * S_LEN;
    const int t = threadIdx.x, wave = t >> 6, lane = t & 63;
    const int wm = (wave >> 1) * 64, wn = (wave & 1) * 64;
    const int lg = lane >> 4, lr = lane & 15;
    const int row0 = qt * 128 + wm + 4 * lg;
    const int col0 = kt * 128 + wn + lr;

#pragma unroll
    for (int i = 0; i < 4; ++i) {
#pragma unroll
        for (int r = 0; r < 4; ++r) {
            const int row = row0 + i * 16 + r;
            float s = 0.f;
#pragma unroll
            for (int j = 0; j < 4; ++j) {
                const int col = col0 + j * 16;
                float p = (col <= row) ? __expf(acc[i][j][r] * ATT_SCALE) : 0.f;
                s += p;
                Pb[(long)row * S_LEN + col] = (_Float16)p;
            }
#pragma unroll
            for (int off = 1; off < 16; off <<= 1) s += __shfl_xor(s, off, 64);
            if (lr == 0) atomicAdd(&rsb[row], s);
        }
    }
}

// ---------------------------------------------------------------------------
// 6) O = (P @ V) / row_sum, split-K + XCD balance (m97 core; unchanged).
// ---------------------------------------------------------------------------
__global__ __launch_bounds__(256) void pv_kernel(const _Float16* __restrict__ P,
                                                 const _Float16* __restrict__ Vt,
                                                 const float* __restrict__ row_sum,
                                                 float* __restrict__ O)
{
    const int xcd = blockIdx.x & 7;
    int r = blockIdx.x >> 3;              // 0..95
    const int b = r / 24;  r %= 24;
    const int j = r >> 3;
    const int nt = r & 7;
    const int sl = (j == 0) ? (7 - xcd) : (j == 1 ? 8 + 2 * xcd : 9 + 2 * xcd);

    int qt, k0s, ks;
    if (sl < 8) { qt = sl; k0s = 0; ks = (qt + 1) * 4; }
    else {
        const int e = sl - 8;
        qt = 8 + (e >> 1);
        ks = (qt + 1) * 2;
        k0s = (e & 1) * ks;
    }

    f32x4 acc[4][4];
#pragma unroll
    for (int i = 0; i < 4; ++i)
#pragma unroll
        for (int jj = 0; jj < 4; ++jj) acc[i][jj] = (f32x4){0.f, 0.f, 0.f, 0.f};

    const _Float16* Ag = P + ((long)b * S_LEN + qt * 128) * S_LEN + k0s * 32;
    const _Float16* Bg = Vt + (long)b * D_DIM * S_LEN + (long)nt * 128 * S_LEN + k0s * 32;
    gemm_core(Ag, Bg, S_LEN, S_LEN, ks, acc);

    float* Ob = O + (long)b * S_LEN * D_DIM;
    const float* rsb = row_sum + (long)b * S_LEN;
    const int t = threadIdx.x, wave = t >> 6, lane = t & 63;
    const int wm = (wave >> 1) * 64, wn = (wave & 1) * 64;
    const int lg = lane >> 4, lr = lane & 15;
    const long row0 = qt * 128 + wm + 4 * lg;
    const long col0 = (long)nt * 128 + wn + lr;

    if (sl < 8) {
#pragma unroll
        for (int i = 0; i < 4; ++i)
#pragma unroll
            for (int rr = 0; rr < 4; ++rr) {
                const float inv = 1.f / rsb[row0 + i * 16 + rr];
#pragma unroll
                for (int jj = 0; jj < 4; ++jj)
                    Ob[(row0 + i * 16 + rr) * D_DIM + col0 + jj * 16] = acc[i][jj][rr] * inv;
            }
    } else {
#pragma unroll
        for (int i = 0; i < 4; ++i)
#pragma unroll
            for (int rr = 0; rr < 4; ++rr) {
                const float inv = 1.f / rsb[row0 + i * 16 + rr];
#pragma unroll
                for (int jj = 0; jj < 4; ++jj)
                    atomicAdd(&Ob[(row0 + i * 16 + rr) * D_DIM + col0 + jj * 16],
                              acc[i][jj][rr] * inv);
            }
    }
}

// ---------------------------------------------------------------------------
// Workspace layout (MiB offsets), total ~119 MiB:
//   Q [0,16) K [16,32) V [32,48) Vt [48,64) Xh [64,80) Wt [80,86)
//   P [86,118)  row_sum [118, 118+32KiB)
// ---------------------------------------------------------------------------
extern "C" void kernel_launch(void* const* d_in, const int* in_sizes, int n_in,
                              void* d_out, int out_size, void* d_ws, size_t ws_size,
                              hipStream_t stream)
{
    const float* x  = (const float*)d_in[0];
    const float* Wq = (const float*)d_in[1];
    const float* Wk = (const float*)d_in[2];
    const float* Wv = (const float*)d_in[3];
    float* out = (float*)d_out;

    char* ws = (char*)d_ws;
    const long MiB = 1024 * 1024;
    _Float16* Q  = (_Float16*)(ws + 0 * MiB);
    _Float16* K  = (_Float16*)(ws + 16 * MiB);
    _Float16* V  = (_Float16*)(ws + 32 * MiB);
    _Float16* Vt = (_Float16*)(ws + 48 * MiB);
    _Float16* Xh = (_Float16*)(ws + 64 * MiB);
    _Float16* Wt = (_Float16*)(ws + 80 * MiB);
    _Float16* P  = (_Float16*)(ws + 86 * MiB);
    float*    RS = (float*)   (ws + 118 * MiB);

    const int nX = in_sizes[0];   // 8388608

    zero_sums_kernel<<<dim3(NB * S_LEN / 256), dim3(256), 0, stream>>>(RS);
    zero_out_kernel<<<dim3(2048), dim3(256), 0, stream>>>((float4*)out,
                                                          (long)NB * S_LEN * D_DIM / 4);
    cast_x_kernel<<<dim3((nX / 4 + 255) / 256), dim3(256), 0, stream>>>(x, Xh, nX);
    transpose_w_kernel<<<dim3(32, 32, 3), dim3(32, 8), 0, stream>>>(Wq, Wk, Wv, Wt);
    proj_kernel<<<dim3(768), dim3(512), 0, stream>>>(Xh, Wt, Q, K, V);
    transpose_v_kernel<<<dim3(16, 32, 4), dim3(256), 0, stream>>>(V, Vt);
    scores_exp_kernel<<<dim3(544), dim3(256), 0, stream>>>(Q, K, P, RS);
    pv_kernel<<<dim3(768), dim3(256), 0, stream>>>(P, Vt, RS, out);
}

// Round 8
// 174.929 us; speedup vs baseline: 1.1400x; 1.0752x over previous
//
#include <hip/hip_runtime.h>

typedef _Float16 half8 __attribute__((ext_vector_type(8)));
typedef _Float16 half4 __attribute__((ext_vector_type(4)));
typedef float f32x4 __attribute__((ext_vector_type(4)));

#define ATT_SCALE 0.03125f   // 1/sqrt(1024)
#define S_LEN 2048
#define D_DIM 1024
#define NB 4

// async 16B HBM -> LDS copy (gfx950 global_load_lds_dwordx4).
// LDS dest must be wave-uniform base; HW adds lane*16.
__device__ __forceinline__ void async_cp16(const _Float16* g, _Float16* l)
{
    __builtin_amdgcn_global_load_lds(
        (const __attribute__((address_space(1))) void*)g,
        (__attribute__((address_space(3))) void*)l, 16, 0, 0);
}

// ---------------------------------------------------------------------------
// Shared GEMM core, BK=64 variant of the m97 structure (2 barriers per
// K-step, gload_lds staging, multi-block overlap). 256 thr / 4 waves, tile
// 128x128, K-step 64 -> HALF the barrier/drain events of BK=32.
// LDS 32 KiB -> ~4 blocks/CU co-resident (wave-level overlap hides drains).
// T2 XOR-swizzle byte^=(row&7)<<4 applied on the per-lane global SOURCE and
// the ds_read address (linear LDS dest; rule 21) -> 0 bank conflicts.
// Wave w owns a 64x64 quadrant: 4x4 frags of 16x16, mfma_f32_16x16x32_f16,
// two K-halves (kk=0,1) per step.
// ---------------------------------------------------------------------------
__device__ __forceinline__ void gemm_core64(const _Float16* __restrict__ Ag,
                                            const _Float16* __restrict__ Bg,
                                            int lda, int ldb, int ksteps64,
                                            f32x4 acc[4][4])
{
    __shared__ _Float16 As[128 * 64];
    __shared__ _Float16 Bs[128 * 64];

    const int t    = threadIdx.x;
    const int wave = t >> 6;
    const int lane = t & 63;
    const int wm   = (wave >> 1) * 64;
    const int wn   = (wave & 1) * 64;
    const int lg   = lane >> 4;    // 16-lane group 0..3
    const int lr   = lane & 15;

    // staging: instr i (i=0..3 per matrix) covers rows i*32..i*32+31.
    // thread t covers row i*32 + (t>>3); linear LDS col-group (t&7);
    // swizzled global col-group (t&7)^(row&7) with row&7 == (t>>3)&7.
    const int tr = t >> 3;
    const int tc = ((t & 7) ^ (tr & 7)) * 8;       // halves
    const int ldso = wave * 512;                   // halves; + i*2048

    const _Float16* ap0 = Ag + (long)(0 * 32 + tr) * lda + tc;
    const _Float16* ap1 = Ag + (long)(1 * 32 + tr) * lda + tc;
    const _Float16* ap2 = Ag + (long)(2 * 32 + tr) * lda + tc;
    const _Float16* ap3 = Ag + (long)(3 * 32 + tr) * lda + tc;
    const _Float16* bp0 = Bg + (long)(0 * 32 + tr) * ldb + tc;
    const _Float16* bp1 = Bg + (long)(1 * 32 + tr) * ldb + tc;
    const _Float16* bp2 = Bg + (long)(2 * 32 + tr) * ldb + tc;
    const _Float16* bp3 = Bg + (long)(3 * 32 + tr) * ldb + tc;

    const int arow = wm + lr;      // + mf*16
    const int brow = wn + lr;      // + nf*16

    for (int ks = 0; ks < ksteps64; ++ks) {
        __syncthreads();   // all waves done reading previous tile
        async_cp16(ap0, As + 0 * 2048 + ldso);
        async_cp16(ap1, As + 1 * 2048 + ldso);
        async_cp16(ap2, As + 2 * 2048 + ldso);
        async_cp16(ap3, As + 3 * 2048 + ldso);
        async_cp16(bp0, Bs + 0 * 2048 + ldso);
        async_cp16(bp1, Bs + 1 * 2048 + ldso);
        async_cp16(bp2, Bs + 2 * 2048 + ldso);
        async_cp16(bp3, Bs + 3 * 2048 + ldso);
        __syncthreads();   // compiler drains vmcnt(0) before s_barrier

        ap0 += 64; ap1 += 64; ap2 += 64; ap3 += 64;
        bp0 += 64; bp1 += 64; bp2 += 64; bp3 += 64;

#pragma unroll
        for (int kk = 0; kk < 2; ++kk) {
            half8 af[4], bf[4];
#pragma unroll
            for (int mf = 0; mf < 4; ++mf) {
                const int row = arow + mf * 16;
                const int hof = (kk * 32 + lg * 8) ^ ((row & 7) * 8);
                af[mf] = *(const half8*)&As[row * 64 + hof];
            }
#pragma unroll
            for (int nf = 0; nf < 4; ++nf) {
                const int row = brow + nf * 16;
                const int hof = (kk * 32 + lg * 8) ^ ((row & 7) * 8);
                bf[nf] = *(const half8*)&Bs[row * 64 + hof];
            }
#pragma unroll
            for (int mf = 0; mf < 4; ++mf)
#pragma unroll
                for (int nf = 0; nf < 4; ++nf)
                    acc[mf][nf] = __builtin_amdgcn_mfma_f32_16x16x32_f16(
                        af[mf], bf[nf], acc[mf][nf], 0, 0, 0);
        }
    }
}

// ---------------------------------------------------------------------------
// 0) fused init: cast x fp32->fp16, zero out, zero row sums. One launch.
//    grid 8192 x 256: thread i handles float4 slot i of x-cast and of out.
// ---------------------------------------------------------------------------
__global__ void init_kernel(const float* __restrict__ X, _Float16* __restrict__ Xh,
                            float4* __restrict__ out, float* __restrict__ rs)
{
    const int i = blockIdx.x * 256 + threadIdx.x;   // 0 .. 2097151
    float4 v = ((const float4*)X)[i];
    half4 h;
    h.x = (_Float16)v.x; h.y = (_Float16)v.y; h.z = (_Float16)v.z; h.w = (_Float16)v.w;
    ((half4*)Xh)[i] = h;
    out[i] = (float4){0.f, 0.f, 0.f, 0.f};
    if (i < NB * S_LEN) rs[i] = 0.f;
}

// ---------------------------------------------------------------------------
// 2) transpose+cast Wq/Wk/Wv [k][n] fp32 -> Wt [w][n][k] fp16
// ---------------------------------------------------------------------------
__global__ void transpose_w_kernel(const float* __restrict__ Wq,
                                   const float* __restrict__ Wk,
                                   const float* __restrict__ Wv,
                                   _Float16* __restrict__ Wt)
{
    __shared__ float tile[32][33];
    const int n0 = blockIdx.x * 32, k0 = blockIdx.y * 32, w = blockIdx.z;
    const float* Wsrc = (w == 0) ? Wq : (w == 1) ? Wk : Wv;
    _Float16* dst = Wt + (long)w * D_DIM * D_DIM;
    const int tx = threadIdx.x, ty = threadIdx.y;
#pragma unroll
    for (int j = 0; j < 4; ++j)
        tile[ty + 8 * j][tx] = Wsrc[(long)(k0 + ty + 8 * j) * D_DIM + n0 + tx];
    __syncthreads();
#pragma unroll
    for (int j = 0; j < 4; ++j)
        dst[(long)(n0 + ty + 8 * j) * D_DIM + k0 + tx] = (_Float16)tile[tx][ty + 8 * j];
}

// ---------------------------------------------------------------------------
// 3) QKV projection: [8192x1024] @ Wt[w] -> Q/K/V fp16. 128x128 tiles,
//    grid 1536 with bijective XCD swizzle (round-4 proven; FETCH 43 MB).
// ---------------------------------------------------------------------------
__global__ __launch_bounds__(256) void proj_kernel(const _Float16* __restrict__ Xh,
                                                   const _Float16* __restrict__ Wt,
                                                   _Float16* __restrict__ Q,
                                                   _Float16* __restrict__ K,
                                                   _Float16* __restrict__ V)
{
    const int flat = blockIdx.x;
    const int swz  = (flat & 7) * 192 + (flat >> 3);   // nwg=1536
    const int nt = swz & 7, mt = (swz >> 3) & 63, w = swz >> 9;

    f32x4 acc[4][4];
#pragma unroll
    for (int i = 0; i < 4; ++i)
#pragma unroll
        for (int j = 0; j < 4; ++j) acc[i][j] = (f32x4){0.f, 0.f, 0.f, 0.f};

    const _Float16* Ag = Xh + (long)mt * 128 * D_DIM;
    const _Float16* Bg = Wt + (long)w * D_DIM * D_DIM + (long)nt * 128 * D_DIM;
    gemm_core64(Ag, Bg, D_DIM, D_DIM, D_DIM / 64, acc);

    _Float16* C = (w == 0) ? Q : (w == 1) ? K : V;
    const int t = threadIdx.x, wave = t >> 6, lane = t & 63;
    const int wm = (wave >> 1) * 64, wn = (wave & 1) * 64;
    const int lg = lane >> 4, lr = lane & 15;
    const long row0 = (long)mt * 128 + wm + 4 * lg;
    const long col0 = (long)nt * 128 + wn + lr;
#pragma unroll
    for (int i = 0; i < 4; ++i)
#pragma unroll
        for (int j = 0; j < 4; ++j)
#pragma unroll
            for (int r = 0; r < 4; ++r)
                C[(row0 + i * 16 + r) * D_DIM + col0 + j * 16] = (_Float16)acc[i][j][r];
}

// ---------------------------------------------------------------------------
// 4) transpose V [b][s][d] -> Vt [b][d][s] (fp16), half8 both ways.
// ---------------------------------------------------------------------------
__global__ __launch_bounds__(256) void transpose_v_kernel(const _Float16* __restrict__ V,
                                                          _Float16* __restrict__ Vt)
{
    __shared__ _Float16 tile[64][72];
    const int d0 = blockIdx.x * 64, s0 = blockIdx.y * 64;
    const long b = blockIdx.z;
    const _Float16* Vb = V + b * S_LEN * D_DIM;
    _Float16* Vtb = Vt + b * D_DIM * S_LEN;
    const int t = threadIdx.x;
    const int sr = t >> 3, c8 = (t & 7) * 8;

    *(half8*)&tile[sr][c8]      = *(const half8*)&Vb[(long)(s0 + sr) * D_DIM + d0 + c8];
    *(half8*)&tile[sr + 32][c8] = *(const half8*)&Vb[(long)(s0 + sr + 32) * D_DIM + d0 + c8];
    __syncthreads();

    const int dr = t >> 3, s8 = (t & 7) * 8;
    half8 o0, o1;
#pragma unroll
    for (int e = 0; e < 8; ++e) {
        o0[e] = tile[s8 + e][dr];
        o1[e] = tile[s8 + e][dr + 32];
    }
    *(half8*)&Vtb[(long)(d0 + dr) * S_LEN + s0 + s8]      = o0;
    *(half8*)&Vtb[(long)(d0 + dr + 32) * S_LEN + s0 + s8] = o1;
}

// ---------------------------------------------------------------------------
// 5) fused scores+exp: P = exp(scale*QK^T) (causal, UNNORMALIZED, fp16),
//    row sums via atomicAdd. Triangular 544-block grid, XCD-balanced.
// ---------------------------------------------------------------------------
__global__ __launch_bounds__(256) void scores_exp_kernel(const _Float16* __restrict__ Q,
                                                         const _Float16* __restrict__ K,
                                                         _Float16* __restrict__ P,
                                                         float* __restrict__ row_sum)
{
    const int xcd = blockIdx.x & 7;
    const int idx = blockIdx.x >> 3;      // 0..67
    const int b   = idx / 17;
    const int l   = idx % 17;
    int qt, kt;
    if (l <= xcd) { qt = xcd;      kt = l; }
    else          { qt = 15 - xcd; kt = l - xcd - 1; }

    f32x4 acc[4][4];
#pragma unroll
    for (int i = 0; i < 4; ++i)
#pragma unroll
        for (int j = 0; j < 4; ++j) acc[i][j] = (f32x4){0.f, 0.f, 0.f, 0.f};

    const _Float16* Ag = Q + ((long)b * S_LEN + qt * 128) * D_DIM;
    const _Float16* Bg = K + ((long)b * S_LEN + kt * 128) * D_DIM;
    gemm_core64(Ag, Bg, D_DIM, D_DIM, D_DIM / 64, acc);

    _Float16* Pb = P + (long)b * S_LEN * S_LEN;
    float* rsb = row_sum + (long)b * S_LEN;
    const int t = threadIdx.x, wave = t >> 6, lane = t & 63;
    const int wm = (wave >> 1) * 64, wn = (wave & 1) * 64;
    const int lg = lane >> 4, lr = lane & 15;
    const int row0 = qt * 128 + wm + 4 * lg;
    const int col0 = kt * 128 + wn + lr;

#pragma unroll
    for (int i = 0; i < 4; ++i) {
#pragma unroll
        for (int r = 0; r < 4; ++r) {
            const int row = row0 + i * 16 + r;
            float s = 0.f;
#pragma unroll
            for (int j = 0; j < 4; ++j) {
                const int col = col0 + j * 16;
                float p = (col <= row) ? __expf(acc[i][j][r] * ATT_SCALE) : 0.f;
                s += p;
                Pb[(long)row * S_LEN + col] = (_Float16)p;
            }
#pragma unroll
            for (int off = 1; off < 16; off <<= 1) s += __shfl_xor(s, off, 64);
            if (lr == 0) atomicAdd(&rsb[row], s);
        }
    }
}

// ---------------------------------------------------------------------------
// 6) O = (P @ V) / row_sum, split-K + XCD balance (round-4 mapping, BK=64:
//    full row qt<8 = (qt+1)*2 steps; halves qt>=8 = (qt+1) steps each).
// ---------------------------------------------------------------------------
__global__ __launch_bounds__(256) void pv_kernel(const _Float16* __restrict__ P,
                                                 const _Float16* __restrict__ Vt,
                                                 const float* __restrict__ row_sum,
                                                 float* __restrict__ O)
{
    const int xcd = blockIdx.x & 7;
    int r = blockIdx.x >> 3;              // 0..95
    const int b = r / 24;  r %= 24;
    const int j = r >> 3;
    const int nt = r & 7;
    const int sl = (j == 0) ? (7 - xcd) : (j == 1 ? 8 + 2 * xcd : 9 + 2 * xcd);

    int qt, k0, ks64;
    if (sl < 8) { qt = sl; k0 = 0; ks64 = (qt + 1) * 2; }
    else {
        const int e = sl - 8;
        qt = 8 + (e >> 1);
        ks64 = qt + 1;
        k0 = (e & 1) * ks64 * 64;
    }

    f32x4 acc[4][4];
#pragma unroll
    for (int i = 0; i < 4; ++i)
#pragma unroll
        for (int jj = 0; jj < 4; ++jj) acc[i][jj] = (f32x4){0.f, 0.f, 0.f, 0.f};

    const _Float16* Ag = P + ((long)b * S_LEN + qt * 128) * S_LEN + k0;
    const _Float16* Bg = Vt + (long)b * D_DIM * S_LEN + (long)nt * 128 * S_LEN + k0;
    gemm_core64(Ag, Bg, S_LEN, S_LEN, ks64, acc);

    float* Ob = O + (long)b * S_LEN * D_DIM;
    const float* rsb = row_sum + (long)b * S_LEN;
    const int t = threadIdx.x, wave = t >> 6, lane = t & 63;
    const int wm = (wave >> 1) * 64, wn = (wave & 1) * 64;
    const int lg = lane >> 4, lr = lane & 15;
    const long row0 = qt * 128 + wm + 4 * lg;
    const long col0 = (long)nt * 128 + wn + lr;

    if (sl < 8) {
#pragma unroll
        for (int i = 0; i < 4; ++i)
#pragma unroll
            for (int rr = 0; rr < 4; ++rr) {
                const float inv = 1.f / rsb[row0 + i * 16 + rr];
#pragma unroll
                for (int jj = 0; jj < 4; ++jj)
                    Ob[(row0 + i * 16 + rr) * D_DIM + col0 + jj * 16] = acc[i][jj][rr] * inv;
            }
    } else {
#pragma unroll
        for (int i = 0; i < 4; ++i)
#pragma unroll
            for (int rr = 0; rr < 4; ++rr) {
                const float inv = 1.f / rsb[row0 + i * 16 + rr];
#pragma unroll
                for (int jj = 0; jj < 4; ++jj)
                    atomicAdd(&Ob[(row0 + i * 16 + rr) * D_DIM + col0 + jj * 16],
                              acc[i][jj][rr] * inv);
            }
    }
}

// ---------------------------------------------------------------------------
// Workspace layout (MiB offsets), total ~119 MiB:
//   Q [0,16) K [16,32) V [32,48) Vt [48,64) Xh [64,80) Wt [80,86)
//   P [86,118)  row_sum [118, 118+32KiB)
// ---------------------------------------------------------------------------
extern "C" void kernel_launch(void* const* d_in, const int* in_sizes, int n_in,
                              void* d_out, int out_size, void* d_ws, size_t ws_size,
                              hipStream_t stream)
{
    const float* x  = (const float*)d_in[0];
    const float* Wq = (const float*)d_in[1];
    const float* Wk = (const float*)d_in[2];
    const float* Wv = (const float*)d_in[3];
    float* out = (float*)d_out;

    char* ws = (char*)d_ws;
    const long MiB = 1024 * 1024;
    _Float16* Q  = (_Float16*)(ws + 0 * MiB);
    _Float16* K  = (_Float16*)(ws + 16 * MiB);
    _Float16* V  = (_Float16*)(ws + 32 * MiB);
    _Float16* Vt = (_Float16*)(ws + 48 * MiB);
    _Float16* Xh = (_Float16*)(ws + 64 * MiB);
    _Float16* Wt = (_Float16*)(ws + 80 * MiB);
    _Float16* P  = (_Float16*)(ws + 86 * MiB);
    float*    RS = (float*)   (ws + 118 * MiB);

    // x has 8388608 floats = 2097152 float4; out identical count.
    init_kernel<<<dim3(8192), dim3(256), 0, stream>>>(x, Xh, (float4*)out, RS);
    transpose_w_kernel<<<dim3(32, 32, 3), dim3(32, 8), 0, stream>>>(Wq, Wk, Wv, Wt);
    proj_kernel<<<dim3(1536), dim3(256), 0, stream>>>(Xh, Wt, Q, K, V);
    transpose_v_kernel<<<dim3(16, 32, 4), dim3(256), 0, stream>>>(V, Vt);
    scores_exp_kernel<<<dim3(544), dim3(256), 0, stream>>>(Q, K, P, RS);
    pv_kernel<<<dim3(768), dim3(256), 0, stream>>>(P, Vt, RS, out);
}